// Round 1
// baseline (9328.027 us; speedup 1.0000x reference)
//
#include <hip/hip_runtime.h>
#include <hip/hip_bf16.h>

#define DMODEL 256
#define S_TOT  70
#define BATCH  128
#define HEADS  8
#define DHEAD  32
#define PAST_N 50
#define FUT_N  20
#define LAYERS 3
#define FFD    1024

#define BM 32
#define BN 64
#define BK 16

__device__ __forceinline__ float wave_sum64(float v) {
#pragma unroll
  for (int off = 32; off > 0; off >>= 1) v += __shfl_xor(v, off, 64);
  return v;
}
__device__ __forceinline__ float wave_max64(float v) {
#pragma unroll
  for (int off = 32; off > 0; off >>= 1) v = fmaxf(v, __shfl_xor(v, off, 64));
  return v;
}
__device__ __forceinline__ float gelu_f(float x) {
  return 0.5f * x * (1.0f + erff(x * 0.7071067811865476f));
}
// block = 256 threads, one row of 256 elements; returns normalized value for this thread's element
__device__ __forceinline__ float ln_norm_256(float x, float g, float b, float* sbuf, int tid) {
  float s = wave_sum64(x);
  if ((tid & 63) == 0) sbuf[tid >> 6] = s;
  __syncthreads();
  float mean = (sbuf[0] + sbuf[1] + sbuf[2] + sbuf[3]) * (1.0f / 256.0f);
  __syncthreads();
  float d = x - mean;
  float vs = wave_sum64(d * d);
  if ((tid & 63) == 0) sbuf[tid >> 6] = vs;
  __syncthreads();
  float var = (sbuf[0] + sbuf[1] + sbuf[2] + sbuf[3]) * (1.0f / 256.0f);
  return d * rsqrtf(var + 1e-5f) * g + b;
}

// C = A(MxK) @ W(NxK)^T + bias  [+ R]  [gelu]
// outmode 0: C[row*N+n]
// outmode 1: n<256 -> qout ; 256..511 -> kcache append (bf16); 512..767 -> vcache append
// outmode 2: 1536 cols -> 6 bf16 slabs (CA K/V for 3 layers), slab j = n>>8
// row -> (b = row / rows_per_b, t = pos_base + row % rows_per_b) for cache addressing.
__global__ __launch_bounds__(256) void k_gemm(
    const float* __restrict__ A, const float* __restrict__ W,
    const float* __restrict__ bias, const float* __restrict__ Rres,
    float* __restrict__ C, int M, int N, int K, int act, int outmode,
    float* __restrict__ qout, __hip_bfloat16* __restrict__ kc,
    __hip_bfloat16* __restrict__ vc, __hip_bfloat16* __restrict__ c6,
    int rows_per_b, int pos_base)
{
  __shared__ float As[BK][BM + 2];  // [16][34]
  __shared__ float Ws[BK][BN + 4];  // [16][68]
  const int tid = threadIdx.x;
  const int bm0 = blockIdx.y * BM;
  const int bn0 = blockIdx.x * BN;
  const int r = tid >> 4, c = tid & 15;
  const int am = tid >> 3, ak = (tid & 7) << 1;
  const int wn = tid >> 2, wk = (tid & 3) << 2;
  const float* Aptr = A + (size_t)(bm0 + am) * K + ak;
  const float* Wptr = W + (size_t)(bn0 + wn) * K + wk;
  float acc[2][4] = {{0.f, 0.f, 0.f, 0.f}, {0.f, 0.f, 0.f, 0.f}};
  for (int k0 = 0; k0 < K; k0 += BK) {
    float2 av = *(const float2*)(Aptr + k0);
    float4 wv = *(const float4*)(Wptr + k0);
    As[ak][am] = av.x;  As[ak + 1][am] = av.y;
    Ws[wk][wn] = wv.x;  Ws[wk + 1][wn] = wv.y;
    Ws[wk + 2][wn] = wv.z;  Ws[wk + 3][wn] = wv.w;
    __syncthreads();
#pragma unroll
    for (int kk = 0; kk < BK; kk++) {
      const float2 a = *(const float2*)&As[kk][r << 1];
      const float4 w = *(const float4*)&Ws[kk][c << 2];
      acc[0][0] += a.x * w.x; acc[0][1] += a.x * w.y;
      acc[0][2] += a.x * w.z; acc[0][3] += a.x * w.w;
      acc[1][0] += a.y * w.x; acc[1][1] += a.y * w.y;
      acc[1][2] += a.y * w.z; acc[1][3] += a.y * w.w;
    }
    __syncthreads();
  }
#pragma unroll
  for (int i = 0; i < 2; i++) {
    const int row = bm0 + (r << 1) + i;
    const int b = row / rows_per_b;
    const int t = pos_base + row % rows_per_b;
#pragma unroll
    for (int j = 0; j < 4; j++) {
      const int n = bn0 + (c << 2) + j;
      float v = acc[i][j] + bias[n];
      if (Rres) v += Rres[(size_t)row * N + n];
      if (act) v = gelu_f(v);
      if (outmode == 0) {
        C[(size_t)row * N + n] = v;
      } else if (outmode == 1) {
        if (n < 256) qout[(size_t)row * DMODEL + n] = v;
        else if (n < 512) kc[((size_t)b * S_TOT + t) * DMODEL + (n - 256)] = __float2bfloat16(v);
        else vc[((size_t)b * S_TOT + t) * DMODEL + (n - 512)] = __float2bfloat16(v);
      } else {
        const int j6 = n >> 8;
        c6[(size_t)j6 * ((size_t)BATCH * S_TOT * DMODEL) +
           ((size_t)b * S_TOT + t) * DMODEL + (n & 255)] = __float2bfloat16(v);
      }
    }
  }
}

// one block (64 thr) per (query row, head); causal attention over keys 0..t
__global__ __launch_bounds__(64) void k_attn(
    const float* __restrict__ qbuf, const __hip_bfloat16* __restrict__ kc,
    const __hip_bfloat16* __restrict__ vc, float* __restrict__ outb,
    int rows_per_b, int pos_base)
{
  __shared__ float qs[DHEAD];
  __shared__ float ss[S_TOT];
  const int bid = blockIdx.x;
  const int h = bid & (HEADS - 1);
  const int row = bid >> 3;
  const int b = row / rows_per_b;
  const int t = pos_base + row % rows_per_b;
  const int nk = t + 1;
  const int lane = threadIdx.x;
  if (lane < DHEAD) qs[lane] = qbuf[(size_t)row * DMODEL + h * DHEAD + lane];
  __syncthreads();
  float mx = -1e30f;
  for (int k0 = lane; k0 < nk; k0 += 64) {
    const __hip_bfloat16* kp = kc + ((size_t)b * S_TOT + k0) * DMODEL + h * DHEAD;
    float s = 0.f;
#pragma unroll
    for (int i = 0; i < DHEAD; i++) s += qs[i] * __bfloat162float(kp[i]);
    s *= 0.17677669529663687f;  // 1/sqrt(32)
    ss[k0] = s;
    mx = fmaxf(mx, s);
  }
  mx = wave_max64(mx);
  float sum = 0.f;
  for (int k0 = lane; k0 < nk; k0 += 64) {
    float e = expf(ss[k0] - mx);
    ss[k0] = e;
    sum += e;
  }
  sum = wave_sum64(sum);
  __syncthreads();
  const float inv = 1.0f / sum;
  if (lane < DHEAD) {
    float o = 0.f;
    for (int k0 = 0; k0 < nk; k0++)
      o += ss[k0] * __bfloat162float(vc[((size_t)b * S_TOT + k0) * DMODEL + h * DHEAD + lane]);
    outb[(size_t)row * DMODEL + h * DHEAD + lane] = o * inv;
  }
}

__global__ __launch_bounds__(256) void k_ln(
    const float* __restrict__ Z, const float* __restrict__ g,
    const float* __restrict__ b, float* __restrict__ out)
{
  __shared__ float sbuf[4];
  const int row = blockIdx.x, tid = threadIdx.x;
  float x = Z[(size_t)row * DMODEL + tid];
  out[(size_t)row * DMODEL + tid] = ln_norm_256(x, g[tid], b[tid], sbuf, tid);
}

__global__ __launch_bounds__(256) void k_embed(
    const float* __restrict__ past, const float* __restrict__ in_W,
    const float* __restrict__ in_b, const float* __restrict__ pos_emb,
    const float* __restrict__ ln_w, const float* __restrict__ ln_b,
    float* __restrict__ Aout)
{
  __shared__ float sbuf[4];
  const int rowid = blockIdx.x;
  const int b = rowid / PAST_N, t = rowid % PAST_N;
  const int tid = threadIdx.x;
  float dx = 0.f, dy = 0.f;
  if (t > 0) {
    dx = past[((size_t)b * PAST_N + t) * 2 + 0] - past[((size_t)b * PAST_N + t - 1) * 2 + 0];
    dy = past[((size_t)b * PAST_N + t) * 2 + 1] - past[((size_t)b * PAST_N + t - 1) * 2 + 1];
  }
  float v = in_W[tid * 2 + 0] * dx + in_W[tid * 2 + 1] * dy + in_b[tid] +
            pos_emb[(size_t)t * DMODEL + tid];
  Aout[(size_t)rowid * DMODEL + tid] = ln_norm_256(v, ln_w[tid], ln_b[tid], sbuf, tid);
}

__global__ __launch_bounds__(256) void k_token(
    const float* __restrict__ ndb, const float* __restrict__ in_W,
    const float* __restrict__ in_b, const float* __restrict__ pos_emb,
    const float* __restrict__ ln_w, const float* __restrict__ ln_b,
    float* __restrict__ Aout, int pos)
{
  __shared__ float sbuf[4];
  const int b = blockIdx.x, tid = threadIdx.x;
  float dx = ndb[b * 2 + 0], dy = ndb[b * 2 + 1];
  float v = in_W[tid * 2 + 0] * dx + in_W[tid * 2 + 1] * dy + in_b[tid] +
            pos_emb[(size_t)pos * DMODEL + tid];
  Aout[(size_t)b * DMODEL + tid] = ln_norm_256(v, ln_w[tid], ln_b[tid], sbuf, tid);
}

// rearrange CA K/V projection weights into one 1536x256 matrix (6 slabs: l*2 + {K,V})
__global__ __launch_bounds__(256) void k_prepack(
    const float* __restrict__ caW, const float* __restrict__ cab,
    float* __restrict__ Wckv, float* __restrict__ bckv)
{
  const int n = blockIdx.x, tid = threadIdx.x;
  const int j = n >> 8, dcol = n & 255;
  const int l = j >> 1, kv = j & 1;
  const int srow = l * 768 + 256 + kv * 256 + dcol;
  Wckv[(size_t)n * 256 + tid] = caW[(size_t)srow * 256 + tid];
  if (tid == 0) bckv[n] = cab[l * 768 + 256 + kv * 256 + dcol];
}

// per-batch: nd = x_row @ out_W^T + out_b ; cur += nd ; emit pos ; stash nd for next token
__global__ __launch_bounds__(64) void k_readout(
    const float* __restrict__ X, const float* __restrict__ out_W,
    const float* __restrict__ out_b, const float* __restrict__ past,
    float* __restrict__ cur, float* __restrict__ ndb, float* __restrict__ out,
    int rows_per_b, int s, int init)
{
  const int b = blockIdx.x, lane = threadIdx.x;
  const int row = b * rows_per_b + rows_per_b - 1;
  float p0 = 0.f, p1 = 0.f;
  for (int d = lane; d < DMODEL; d += 64) {
    const float xv = X[(size_t)row * DMODEL + d];
    p0 += xv * out_W[d];
    p1 += xv * out_W[DMODEL + d];
  }
  p0 = wave_sum64(p0);
  p1 = wave_sum64(p1);
  if (lane == 0) {
    const float nd0 = p0 + out_b[0];
    const float nd1 = p1 + out_b[1];
    float c0, c1;
    if (init) {
      c0 = past[((size_t)b * PAST_N + PAST_N - 1) * 2 + 0];
      c1 = past[((size_t)b * PAST_N + PAST_N - 1) * 2 + 1];
    } else {
      c0 = cur[b * 2 + 0];
      c1 = cur[b * 2 + 1];
    }
    c0 += nd0; c1 += nd1;
    cur[b * 2 + 0] = c0; cur[b * 2 + 1] = c1;
    ndb[b * 2 + 0] = nd0; ndb[b * 2 + 1] = nd1;
    out[((size_t)b * FUT_N + s) * 2 + 0] = c0;
    out[((size_t)b * FUT_N + s) * 2 + 1] = c1;
  }
}

extern "C" void kernel_launch(void* const* d_in, const int* in_sizes, int n_in,
                              void* d_out, int out_size, void* d_ws, size_t ws_size,
                              hipStream_t stream)
{
  const float* past    = (const float*)d_in[0];
  const float* in_W    = (const float*)d_in[1];
  const float* in_b    = (const float*)d_in[2];
  const float* pos_emb = (const float*)d_in[3];
  const float* ln0_w   = (const float*)d_in[4];
  const float* ln0_b   = (const float*)d_in[5];
  const float* sa_Wqkv = (const float*)d_in[6];
  const float* sa_bqkv = (const float*)d_in[7];
  const float* sa_Wo   = (const float*)d_in[8];
  const float* sa_bo   = (const float*)d_in[9];
  const float* ca_Wqkv = (const float*)d_in[10];
  const float* ca_bqkv = (const float*)d_in[11];
  const float* ca_Wo   = (const float*)d_in[12];
  const float* ca_bo   = (const float*)d_in[13];
  const float* ff1_W   = (const float*)d_in[14];
  const float* ff1_b   = (const float*)d_in[15];
  const float* ff2_W   = (const float*)d_in[16];
  const float* ff2_b   = (const float*)d_in[17];
  const float* ln1_w   = (const float*)d_in[18];
  const float* ln1_b   = (const float*)d_in[19];
  const float* ln2_w   = (const float*)d_in[20];
  const float* ln2_b   = (const float*)d_in[21];
  const float* ln3_w   = (const float*)d_in[22];
  const float* ln3_b   = (const float*)d_in[23];
  const float* out_W   = (const float*)d_in[24];
  const float* out_b   = (const float*)d_in[25];
  float* out = (float*)d_out;

  const size_t Mpre = (size_t)BATCH * PAST_N;  // 6400
  const size_t slab = (size_t)BATCH * S_TOT * DMODEL;  // 2,293,760

  float* ws_f = (float*)d_ws;
  float* A    = ws_f;
  float* Bb   = A + Mpre * DMODEL;
  float* qb   = Bb + Mpre * DMODEL;
  float* at   = qb + Mpre * DMODEL;
  float* hb   = at + Mpre * DMODEL;
  float* Wckv = hb + Mpre * FFD;
  float* bckv = Wckv + (size_t)1536 * 256;
  float* ndb  = bckv + 1536;
  float* cur  = ndb + 256;
  __hip_bfloat16* Ksa = (__hip_bfloat16*)(cur + 256);
  __hip_bfloat16* Vsa = Ksa + 3 * slab;
  __hip_bfloat16* C6  = Vsa + 3 * slab;

  const size_t need = ((size_t)(C6 + 6 * slab) - (size_t)d_ws);
  if (ws_size < need) return;  // workspace too small -> fail validation cleanly

  auto layer = [&](int l, int M, int rpb, int pbase) {
    const float* Wqkv = sa_Wqkv + (size_t)l * 768 * 256;
    __hip_bfloat16* kcl = Ksa + (size_t)l * slab;
    __hip_bfloat16* vcl = Vsa + (size_t)l * slab;
    // SA qkv (+ cache append)
    k_gemm<<<dim3(768 / BN, M / BM), 256, 0, stream>>>(
        A, Wqkv, sa_bqkv + l * 768, nullptr, nullptr, M, 768, 256, 0, 1,
        qb, kcl, vcl, nullptr, rpb, pbase);
    k_attn<<<M * HEADS, 64, 0, stream>>>(qb, kcl, vcl, at, rpb, pbase);
    k_gemm<<<dim3(256 / BN, M / BM), 256, 0, stream>>>(
        at, sa_Wo + (size_t)l * 65536, sa_bo + l * 256, A, Bb, M, 256, 256, 0, 0,
        nullptr, nullptr, nullptr, nullptr, 1, 0);
    k_ln<<<M, 256, 0, stream>>>(Bb, ln1_w + l * 256, ln1_b + l * 256, A);
    // CA q
    k_gemm<<<dim3(256 / BN, M / BM), 256, 0, stream>>>(
        A, ca_Wqkv + (size_t)l * 768 * 256, ca_bqkv + l * 768, nullptr, qb,
        M, 256, 256, 0, 0, nullptr, nullptr, nullptr, nullptr, 1, 0);
    k_attn<<<M * HEADS, 64, 0, stream>>>(
        qb, C6 + (size_t)(2 * l) * slab, C6 + (size_t)(2 * l + 1) * slab, at, rpb, pbase);
    k_gemm<<<dim3(256 / BN, M / BM), 256, 0, stream>>>(
        at, ca_Wo + (size_t)l * 65536, ca_bo + l * 256, A, Bb, M, 256, 256, 0, 0,
        nullptr, nullptr, nullptr, nullptr, 1, 0);
    k_ln<<<M, 256, 0, stream>>>(Bb, ln2_w + l * 256, ln2_b + l * 256, A);
    // FF
    k_gemm<<<dim3(FFD / BN, M / BM), 256, 0, stream>>>(
        A, ff1_W + (size_t)l * FFD * 256, ff1_b + l * FFD, nullptr, hb,
        M, FFD, 256, 1, 0, nullptr, nullptr, nullptr, nullptr, 1, 0);
    k_gemm<<<dim3(256 / BN, M / BM), 256, 0, stream>>>(
        hb, ff2_W + (size_t)l * 256 * FFD, ff2_b + l * 256, A, Bb, M, 256, FFD, 0, 0,
        nullptr, nullptr, nullptr, nullptr, 1, 0);
    k_ln<<<M, 256, 0, stream>>>(Bb, ln3_w + l * 256, ln3_b + l * 256, A);
  };

  // ---- prefill over past 50 positions ----
  k_prepack<<<1536, 256, 0, stream>>>(ca_Wqkv, ca_bqkv, Wckv, bckv);
  k_embed<<<(int)Mpre, 256, 0, stream>>>(past, in_W, in_b, pos_emb, ln0_w, ln0_b, A);
  // CA K/V caches for all 3 layers from mem (= LN0 output)
  k_gemm<<<dim3(1536 / BN, (int)Mpre / BM), 256, 0, stream>>>(
      A, Wckv, bckv, nullptr, nullptr, (int)Mpre, 1536, 256, 0, 2,
      nullptr, nullptr, nullptr, C6, PAST_N, 0);
  for (int l = 0; l < LAYERS; l++) layer(l, (int)Mpre, PAST_N, 0);
  k_readout<<<BATCH, 64, 0, stream>>>(A, out_W, out_b, past, cur, ndb, out, PAST_N, 0, 1);

  // ---- 19 incremental decode steps ----
  for (int s = 1; s < FUT_N; s++) {
    const int pos = PAST_N - 1 + s;
    k_token<<<BATCH, 256, 0, stream>>>(ndb, in_W, in_b, pos_emb, ln0_w, ln0_b, A, pos);
    k_gemm<<<dim3(1536 / BN, BATCH / BM), 256, 0, stream>>>(
        A, Wckv, bckv, nullptr, nullptr, BATCH, 1536, 256, 0, 2,
        nullptr, nullptr, nullptr, C6, 1, pos);
    for (int l = 0; l < LAYERS; l++) layer(l, BATCH, 1, pos);
    k_readout<<<BATCH, 64, 0, stream>>>(A, out_W, out_b, past, cur, ndb, out, 1, s, 0);
  }
}